// Round 19
// baseline (152.769 us; speedup 1.0000x reference)
//
#include <hip/hip_runtime.h>
#include <math.h>

#define NDST 50000
#define NSRC 50000
#define NEDGE 800000
#define DF 128

#define NBUK 1563          // ceil(NDST/32): dst bucket = dst >> 5
#define NCH 128            // edge chunks
#define EPC (NEDGE / NCH)  // 6250 edges per chunk
#define HN (NBUK * NCH)    // 200064 histogram cells
#define CAP 1536           // per-chunk LDS sort capacity

typedef __attribute__((ext_vector_type(4))) float f32x4;
typedef __attribute__((ext_vector_type(8))) short bf16x8;

__device__ __forceinline__ ushort f2bf(float f) {
    union { float f; unsigned int u; } c; c.f = f;
    unsigned int u = c.u;
    unsigned int r = (u + 0x7fffu + ((u >> 16) & 1u)) >> 16;   // RNE
    return (ushort)r;
}
__device__ __forceinline__ float bflo(unsigned int u) {
    union { unsigned int u; float f; } c; c.u = u << 16; return c.f;
}
__device__ __forceinline__ float bfhi(unsigned int u) {
    union { unsigned int u; float f; } c; c.u = u & 0xffff0000u; return c.f;
}

// ---------------- prep_all: GRID-STRIDE conv fs+fd + weights + coalesced hist zero ----
// Wz is emitted in MFMA FRAGMENT ORDER (R11's verified layout) for the fused
// z2-GEMM inside bucket_sort_agg: entry e=(ks*8+nt)*64+lane holds
// W[n][kb..kb+8), n=nt*16+(lane&15), kb=ks*32+(lane>>4)*8.
#define PB_FS 1500
#define PB_FD 1500
#define PB_W 208           // 4096 frag entries + 16384 W1 + 32768 W3 = 53248 thr
#define PB_Z 196           // HN/4 uint4 one-shot
#define PB_TOT (PB_FS + PB_FD + PB_W + PB_Z)

__global__ void prep_all(const float* __restrict__ fs, unsigned int* __restrict__ fs_b,
                         const float* __restrict__ fd, unsigned int* __restrict__ fd_b,
                         uint4* __restrict__ hist4,
                         const float* __restrict__ W2, const float* __restrict__ W1,
                         const float* __restrict__ W3,
                         ushort* __restrict__ Wzf, ushort* __restrict__ W1_b,
                         ushort* __restrict__ W3_b) {
    int b = blockIdx.x, tid = threadIdx.x;
    if (b < PB_FS + PB_FD) {
        const float* src = (b < PB_FS) ? fs : fd;
        unsigned int* dst = (b < PB_FS) ? fs_b : fd_b;
        int lb = (b < PB_FS) ? b : b - PB_FS;
        const int NU = NSRC * DF / 4;                 // 1.6M units of 4 floats
        for (int u = lb * 256 + tid; u < NU; u += PB_FS * 256) {
            float4 v = ((const float4*)src)[u];
            unsigned int lo = (unsigned int)f2bf(v.x) | ((unsigned int)f2bf(v.y) << 16);
            unsigned int hi = (unsigned int)f2bf(v.z) | ((unsigned int)f2bf(v.w) << 16);
            ((uint2*)dst)[u] = make_uint2(lo, hi);
        }
    } else if (b < PB_FS + PB_FD + PB_W) {
        int i = (b - PB_FS - PB_FD) * 256 + tid;
        if (i < 4096) {                               // Wz fragment entry (8 bf16)
            int e = i, lane = e & 63, nt = (e >> 6) & 7, ks = e >> 9;
            int n = nt * 16 + (lane & 15), kb = ks * 32 + ((lane >> 4) << 3);
            float v[8];
            #pragma unroll
            for (int j = 0; j < 8; ++j) {
                int col = kb + j;
                v[j] = (col < 128) ? (W2[n * 384 + col] + W2[n * 384 + 128 + col])
                                   : W2[n * 384 + 128 + col];
            }
            unsigned int u0 = (unsigned int)f2bf(v[0]) | ((unsigned int)f2bf(v[1]) << 16);
            unsigned int u1 = (unsigned int)f2bf(v[2]) | ((unsigned int)f2bf(v[3]) << 16);
            unsigned int u2 = (unsigned int)f2bf(v[4]) | ((unsigned int)f2bf(v[5]) << 16);
            unsigned int u3 = (unsigned int)f2bf(v[6]) | ((unsigned int)f2bf(v[7]) << 16);
            *(uint4*)(Wzf + (size_t)e * 8) = make_uint4(u0, u1, u2, u3);
        } else if (i < 4096 + 16384) {
            int j = i - 4096;
            W1_b[j] = f2bf(W1[j]);
        } else if (i < 4096 + 16384 + 32768) {
            int j = i - 4096 - 16384;
            W3_b[j] = f2bf(W3[j]);
        }
    } else {
        int i = (b - PB_FS - PB_FD - PB_W) * 256 + tid;   // coalesced uint4 zero
        if (i < HN / 4) hist4[i] = make_uint4(0, 0, 0, 0);
    }
}

// ---------------- histogram (full-grid parallel, chunk from edge index) ----
__global__ void hist_k(const int* __restrict__ dst_idx, int* __restrict__ hist) {
    int e = blockIdx.x * 256 + threadIdx.x;
    if (e < NEDGE)
        atomicAdd(&hist[(dst_idx[e] >> 5) * NCH + (e / EPC)], 1);
}

// ---------------- generic 3-phase exclusive scan ----------------
__global__ void scan_bsums(const int* __restrict__ a, int* __restrict__ bsum, int n) {
    __shared__ int ws[4];
    int i = blockIdx.x * 256 + threadIdx.x;
    int v = (i < n) ? a[i] : 0;
    #pragma unroll
    for (int off = 32; off > 0; off >>= 1) v += __shfl_down(v, off, 64);
    if ((threadIdx.x & 63) == 0) ws[threadIdx.x >> 6] = v;
    __syncthreads();
    if (threadIdx.x == 0) bsum[blockIdx.x] = ws[0] + ws[1] + ws[2] + ws[3];
}

__global__ __launch_bounds__(256)
void scan_mid(const int* __restrict__ bsum, int* __restrict__ bpre, int nb) {
    __shared__ int part[256];
    int t = threadIdx.x;
    int ch = (nb + 255) / 256;
    int lo = t * ch, hi = min(nb, lo + ch);
    int s = 0;
    for (int i = lo; i < hi; ++i) s += bsum[i];
    part[t] = s;
    __syncthreads();
    for (int off = 1; off < 256; off <<= 1) {
        int v = (t >= off) ? part[t - off] : 0;
        __syncthreads();
        part[t] += v;
        __syncthreads();
    }
    int run = (t == 0) ? 0 : part[t - 1];
    for (int i = lo; i < hi; ++i) { bpre[i] = run; run += bsum[i]; }
}

__global__ __launch_bounds__(256)
void scan_final(const int* __restrict__ a, const int* __restrict__ bpre,
                int* __restrict__ out, int n) {
    __shared__ int s[256];
    int b = blockIdx.x, t = threadIdx.x;
    int i = b * 256 + t;
    int v = (i < n) ? a[i] : 0;
    s[t] = v;
    __syncthreads();
    for (int off = 1; off < 256; off <<= 1) {
        int u = (t >= off) ? s[t - off] : 0;
        __syncthreads();
        s[t] += u;
        __syncthreads();
    }
    if (i < n) out[i] = bpre[b] + s[t] - v;
}

// ---------------- partition: bucket-grouped (dlow<<16 | src) pairs ----------------
__global__ __launch_bounds__(256)
void partition_k(const int* __restrict__ src_idx, const int* __restrict__ dst_idx,
                 const int* __restrict__ scanned, unsigned int* __restrict__ pairs) {
    __shared__ int offs_l[NBUK];
    int c = blockIdx.x, tid = threadIdx.x;
    for (int i = tid; i < NBUK; i += 256) offs_l[i] = scanned[i * NCH + c];
    __syncthreads();
    int base = c * EPC;
    for (int e = base + tid; e < base + EPC; e += 256) {
        int d = dst_idx[e];
        int pos = atomicAdd(&offs_l[d >> 5], 1);
        pairs[pos] = (unsigned int)src_idx[e] | ((unsigned int)(d & 31) << 16);
    }
}

// ---------------- bucket aggregate + FUSED z2 GEMM ----------------
// Phase 1 (as before): counting-sort bucket's pairs, register max/sum.
// Phase 2 (new): write mx|sm to a 32x256 bf16 LDS tile, run the 32x128
// z2 = relu([mx|sm] @ Wz^T + b2) GEMM in-block (Wz fragment-order from L2),
// store bf16 h0 directly. mx/sm never touch global memory.
#define ATS 132    // At row stride in uints (528B, 16B-aligned)

__global__ __launch_bounds__(256)
void bucket_sort_agg(const unsigned int* __restrict__ fs_b,
                     const unsigned int* __restrict__ pairs,
                     const int* __restrict__ scanned,
                     const ushort* __restrict__ Wzf, const float* __restrict__ b2,
                     ushort* __restrict__ h0) {
    __shared__ int s_src[CAP];
    __shared__ int s_cnt[32], s_off[32], s_cur[32];
    __shared__ unsigned int At[32 * ATS];   // 16.9 KB: 32 rows x 128 uints (bf16x2)
    int B = blockIdx.x, tid = threadIdx.x;
    int w = tid >> 6, lane = tid & 63;
    int s0 = scanned[B * NCH];
    int s1 = (B + 1 < NBUK) ? scanned[(B + 1) * NCH] : NEDGE;

    float mx0[8], mx1[8], sm0[8], sm1[8];
    #pragma unroll
    for (int j = 0; j < 8; ++j) {
        mx0[j] = -INFINITY; mx1[j] = -INFINITY; sm0[j] = 0.f; sm1[j] = 0.f;
    }

    for (int cs = s0; cs < s1; cs += CAP) {
        int n = min(CAP, s1 - cs);
        if (tid < 32) s_cnt[tid] = 0;
        __syncthreads();
        for (int i = tid; i < n; i += 256)
            atomicAdd(&s_cnt[(pairs[cs + i] >> 16) & 31u], 1);
        __syncthreads();
        if (tid < 32) {                      // wave 0: 32-wide shfl scan
            int v = s_cnt[tid];
            int incl = v;
            #pragma unroll
            for (int d = 1; d < 32; d <<= 1) {
                int o = __shfl_up(incl, d, 64);
                if (tid >= d) incl += o;
            }
            s_off[tid] = incl - v;
            s_cur[tid] = incl - v;
        }
        __syncthreads();
        for (int i = tid; i < n; i += 256) {
            unsigned int p = pairs[cs + i];
            int pos = atomicAdd(&s_cur[(p >> 16) & 31u], 1);
            s_src[pos] = (int)(p & 0xFFFFu);
        }
        __syncthreads();
        #pragma unroll
        for (int j = 0; j < 8; ++j) {
            int dl = w * 8 + j;
            int e = s_off[dl], eend = e + s_cnt[dl];
            for (; e + 7 < eend; e += 8) {          // 8 outstanding row loads
                unsigned int u0 = fs_b[(size_t)s_src[e] * 64 + lane];
                unsigned int u1 = fs_b[(size_t)s_src[e + 1] * 64 + lane];
                unsigned int u2 = fs_b[(size_t)s_src[e + 2] * 64 + lane];
                unsigned int u3 = fs_b[(size_t)s_src[e + 3] * 64 + lane];
                unsigned int u4 = fs_b[(size_t)s_src[e + 4] * 64 + lane];
                unsigned int u5 = fs_b[(size_t)s_src[e + 5] * 64 + lane];
                unsigned int u6 = fs_b[(size_t)s_src[e + 6] * 64 + lane];
                unsigned int u7 = fs_b[(size_t)s_src[e + 7] * 64 + lane];
                float a0 = bflo(u0), c0 = bfhi(u0);
                float a1 = bflo(u1), c1 = bfhi(u1);
                float a2 = bflo(u2), c2 = bfhi(u2);
                float a3 = bflo(u3), c3 = bfhi(u3);
                float a4 = bflo(u4), c4 = bfhi(u4);
                float a5 = bflo(u5), c5 = bfhi(u5);
                float a6 = bflo(u6), c6 = bfhi(u6);
                float a7 = bflo(u7), c7 = bfhi(u7);
                mx0[j] = fmaxf(mx0[j], fmaxf(fmaxf(fmaxf(a0, a1), fmaxf(a2, a3)),
                                             fmaxf(fmaxf(a4, a5), fmaxf(a6, a7))));
                mx1[j] = fmaxf(mx1[j], fmaxf(fmaxf(fmaxf(c0, c1), fmaxf(c2, c3)),
                                             fmaxf(fmaxf(c4, c5), fmaxf(c6, c7))));
                sm0[j] += ((a0 + a1) + (a2 + a3)) + ((a4 + a5) + (a6 + a7));
                sm1[j] += ((c0 + c1) + (c2 + c3)) + ((c4 + c5) + (c6 + c7));
            }
            for (; e + 3 < eend; e += 4) {
                unsigned int u0 = fs_b[(size_t)s_src[e] * 64 + lane];
                unsigned int u1 = fs_b[(size_t)s_src[e + 1] * 64 + lane];
                unsigned int u2 = fs_b[(size_t)s_src[e + 2] * 64 + lane];
                unsigned int u3 = fs_b[(size_t)s_src[e + 3] * 64 + lane];
                float a0 = bflo(u0), c0 = bfhi(u0);
                float a1 = bflo(u1), c1 = bfhi(u1);
                float a2 = bflo(u2), c2 = bfhi(u2);
                float a3 = bflo(u3), c3 = bfhi(u3);
                mx0[j] = fmaxf(fmaxf(fmaxf(mx0[j], a0), a1), fmaxf(a2, a3));
                mx1[j] = fmaxf(fmaxf(fmaxf(mx1[j], c0), c1), fmaxf(c2, c3));
                sm0[j] += (a0 + a1) + (a2 + a3);
                sm1[j] += (c0 + c1) + (c2 + c3);
            }
            for (; e < eend; ++e) {
                unsigned int u = fs_b[(size_t)s_src[e] * 64 + lane];
                float a = bflo(u), c = bfhi(u);
                mx0[j] = fmaxf(mx0[j], a);
                mx1[j] = fmaxf(mx1[j], c);
                sm0[j] += a;
                sm1[j] += c;
            }
        }
        __syncthreads();                     // LDS reused next chunk
    }

    // ---- write mx|sm into At (all 32 rows defined; OOB dsts get zeros) ----
    #pragma unroll
    for (int j = 0; j < 8; ++j) {
        int dl = w * 8 + j;
        float m0 = (mx0[j] == -INFINITY) ? 0.f : mx0[j];
        float m1 = (mx1[j] == -INFINITY) ? 0.f : mx1[j];
        union { float f; unsigned int u; } c0, c1;
        c0.f = m0; c1.f = m1;                // maxima of bf16 values: exact truncation
        At[dl * ATS + lane] = (c0.u >> 16) | (c1.u & 0xFFFF0000u);
        At[dl * ATS + 64 + lane] =
            (unsigned int)f2bf(sm0[j]) | ((unsigned int)f2bf(sm1[j]) << 16);
    }
    __syncthreads();

    // ---- fused z2 GEMM: h0[32x128] = relu([mx|sm] @ Wz^T + b2) ----
    int wm = (w & 1) * 16, wn = (w >> 1) * 64;
    int lrow = lane & 15, rbase = (lane >> 4) * 4;
    f32x4 acc[4];
    #pragma unroll
    for (int ni = 0; ni < 4; ++ni) acc[ni] = (f32x4){0.f, 0.f, 0.f, 0.f};
    #pragma unroll
    for (int ks = 0; ks < 8; ++ks) {
        bf16x8 af = *(const bf16x8*)&At[(wm + lrow) * ATS + ks * 16 + (lane >> 4) * 4];
        #pragma unroll
        for (int ni = 0; ni < 4; ++ni) {
            bf16x8 bf = *(const bf16x8*)(Wzf +
                ((size_t)(ks * 8 + (w >> 1) * 4 + ni) * 64 + lane) * 8);
            acc[ni] = __builtin_amdgcn_mfma_f32_16x16x32_bf16(af, bf, acc[ni], 0, 0, 0);
        }
    }
    int base_d = B * 32;
    #pragma unroll
    for (int ni = 0; ni < 4; ++ni) {
        int n = wn + ni * 16 + lrow;
        float bv = b2[n];
        #pragma unroll
        for (int r = 0; r < 4; ++r) {
            int m = base_d + wm + rbase + r;
            if (m < NDST)
                h0[(size_t)m * 128 + n] = f2bf(fmaxf(acc[ni][r] + bv, 0.f));
        }
    }
}

// ---------------- fused MLP: A2 + B only (A1 lives in bucket_sort_agg now) ----------
// h0 tile is staged into Hs[:,0:128] under A2's compute (loads issued in the
// prologue, ds_writes after A2's epilogue). 12 pipeline steps total (was 20).
#define BM2 32
#define LDH 260    // Hs row stride
#define LDWS 40    // Ws row stride (80B, 16B-aligned)

__global__ __launch_bounds__(256)
void mlp_fused(const ushort* __restrict__ h0, const ushort* __restrict__ fdb,
               const ushort* __restrict__ W1_b, const ushort* __restrict__ W3_b,
               const float* __restrict__ b1, const float* __restrict__ b3,
               float* __restrict__ out) {
    __shared__ ushort Hs[BM2 * LDH];     // 16.6 KB
    __shared__ ushort Ws[128 * LDWS];    // 10.2 KB  -> 26.9 KB total, 5 blocks/CU
    int tid = threadIdx.x;
    int bm = blockIdx.x * BM2;
    int wid = tid >> 6, lane = tid & 63;
    int wm = (wid & 1) * 16, wn = (wid >> 1) * 64;
    int lrow = lane & 15, lk8 = (lane >> 4) * 8;
    int rbase = (lane >> 4) * 4;

    int am0 = min(bm + wm + lrow, NDST - 1);          // clamped; OOB never stored
    int bn[4];
    #pragma unroll
    for (int ni = 0; ni < 4; ++ni) bn[ni] = wn + ni * 16 + lrow;

    int srw = tid >> 1, skw = (tid & 1) * 16;         // W staging coords
    uint4 wr0, wr1;                                    // W regs (one step ahead)
    f32x4 acc[4];

#define STAGE_LOAD(Wb, K, k0) { const ushort* wp = (Wb) + (size_t)srw * (K) + (k0) + skw; \
                                wr0 = *(const uint4*)wp; wr1 = *(const uint4*)(wp + 8); }
#define STAGE_WRITE() { *(uint4*)&Ws[srw * LDWS + skw] = wr0; \
                        *(uint4*)&Ws[srw * LDWS + skw + 8] = wr1; }

    // prologue: W1 step0 + all A2 frags + the h0 tile, all in flight
    STAGE_LOAD(W1_b, 128, 0);
    bf16x8 qA[4];
    #pragma unroll
    for (int k = 0; k < 4; ++k)
        qA[k] = *(const bf16x8*)(fdb + (size_t)am0 * 128 + k * 32 + lk8);
    int u0 = tid * 2, u1 = tid * 2 + 1;               // h0 tile: 512 uint4 total
    int hr0 = u0 >> 4, hc0 = (u0 & 15) * 8;
    int hr1 = u1 >> 4, hc1 = (u1 & 15) * 8;
    int hg0 = min(bm + hr0, NDST - 1), hg1 = min(bm + hr1, NDST - 1);
    uint4 h0a = *(const uint4*)(h0 + (size_t)hg0 * 128 + hc0);
    uint4 h0b = *(const uint4*)(h0 + (size_t)hg1 * 128 + hc1);

    // ---------- phase A2: h[:,128:256] = relu(fd @ W1^T + b1), K=128 ----------
    #pragma unroll
    for (int j = 0; j < 4; ++j) acc[j] = (f32x4){0.f, 0.f, 0.f, 0.f};
    #pragma unroll
    for (int k = 0; k < 4; ++k) {
        if (k) __syncthreads();            // prev step's Ws readers done
        STAGE_WRITE();
        __syncthreads();                   // Ws ready
        if (k < 3) { STAGE_LOAD(W1_b, 128, (k + 1) * 32); }
        else       { STAGE_LOAD(W3_b, 256, 0); }             // phase B's W
        #pragma unroll
        for (int ni = 0; ni < 4; ++ni) {
            bf16x8 bf = *(const bf16x8*)&Ws[bn[ni] * LDWS + lk8];
            acc[ni] = __builtin_amdgcn_mfma_f32_16x16x32_bf16(qA[k], bf, acc[ni], 0, 0, 0);
        }
    }
    #pragma unroll
    for (int ni = 0; ni < 4; ++ni) {
        float bv = b1[bn[ni]];
        #pragma unroll
        for (int r = 0; r < 4; ++r)
            Hs[(wm + rbase + r) * LDH + 128 + bn[ni]] = f2bf(fmaxf(acc[ni][r] + bv, 0.f));
    }
    // stage h0 tile into Hs[:,0:128]
    *(uint4*)&Hs[hr0 * LDH + hc0] = h0a;
    *(uint4*)&Hs[hr1 * LDH + hc1] = h0b;

    // ---------- phase B: out = relu(h @ W3^T + b3), K=256, A from LDS ----------
    #pragma unroll
    for (int j = 0; j < 4; ++j) acc[j] = (f32x4){0.f, 0.f, 0.f, 0.f};
    #pragma unroll
    for (int k = 0; k < 8; ++k) {
        __syncthreads();                   // k=0: all Hs writes visible; else Ws readers done
        STAGE_WRITE();
        __syncthreads();
        if (k < 7) { STAGE_LOAD(W3_b, 256, (k + 1) * 32); }
        bf16x8 af0 = *(const bf16x8*)&Hs[(wm + lrow) * LDH + k * 32 + lk8];
        #pragma unroll
        for (int ni = 0; ni < 4; ++ni) {
            bf16x8 bf = *(const bf16x8*)&Ws[bn[ni] * LDWS + lk8];
            acc[ni] = __builtin_amdgcn_mfma_f32_16x16x32_bf16(af0, bf, acc[ni], 0, 0, 0);
        }
    }
    #pragma unroll
    for (int ni = 0; ni < 4; ++ni) {
        float bv = b3[bn[ni]];
        #pragma unroll
        for (int r = 0; r < 4; ++r) {
            int m = bm + wm + rbase + r;
            if (m < NDST)
                out[(size_t)m * 128 + bn[ni]] = fmaxf(acc[ni][r] + bv, 0.f);
        }
    }
#undef STAGE_LOAD
#undef STAGE_WRITE
}

extern "C" void kernel_launch(void* const* d_in, const int* in_sizes, int n_in,
                              void* d_out, int out_size, void* d_ws, size_t ws_size,
                              hipStream_t stream) {
    const float* feat_src = (const float*)d_in[0];
    const float* feat_dst = (const float*)d_in[1];
    const float* W1 = (const float*)d_in[2];
    const float* b1 = (const float*)d_in[3];
    const float* W2 = (const float*)d_in[4];
    const float* b2 = (const float*)d_in[5];
    const float* W3 = (const float*)d_in[6];
    const float* b3 = (const float*)d_in[7];
    const int* src_idx = (const int*)d_in[8];
    const int* dst_idx = (const int*)d_in[9];

    float* out = (float*)d_out;

    unsigned int* fs_b = (unsigned int*)d_ws;                 // NSRC*64 u32
    unsigned int* fd_b = fs_b + (size_t)NSRC * 64;            // NDST*64 u32
    ushort* h0   = (ushort*)(fd_b + (size_t)NDST * 64);       // NDST*128 bf16
    ushort* Wzf  = h0 + (size_t)NDST * 128;                   // 128*256 (frag order)
    ushort* W1_b = Wzf + 128 * 256;                           // 128*128
    ushort* W3_b = W1_b + 128 * 128;                          // 128*256
    int* hist    = (int*)(W3_b + 128 * 256);                  // HN (16B aligned)
    int* scanned = hist + HN;                                 // HN
    int* bsum    = scanned + HN;                              // 1024
    int* bpre    = bsum + 1024;                               // 1024
    unsigned int* pairs = (unsigned int*)(bpre + 1024);       // NEDGE

    const int NBH = (HN + 255) / 256;   // 782 scan blocks

    // prep: grid-stride feat conversions + weights (Wz frag-order) + hist zero
    prep_all<<<PB_TOT, 256, 0, stream>>>(
        feat_src, fs_b, feat_dst, fd_b, (uint4*)hist, W2, W1, W3, Wzf, W1_b, W3_b);

    // histogram (full-grid) + scan + partition
    hist_k<<<(NEDGE + 255) / 256, 256, 0, stream>>>(dst_idx, hist);
    scan_bsums<<<NBH, 256, 0, stream>>>(hist, bsum, HN);
    scan_mid<<<1, 256, 0, stream>>>(bsum, bpre, NBH);
    scan_final<<<NBH, 256, 0, stream>>>(hist, bpre, scanned, HN);
    partition_k<<<NCH, 256, 0, stream>>>(src_idx, dst_idx, scanned, pairs);

    // aggregation + fused z2 GEMM -> h0 (mx/sm never hit global)
    bucket_sort_agg<<<NBUK, 256, 0, stream>>>(fs_b, pairs, scanned, Wzf, b2, h0);

    // fused MLP (A2 + B): h0 staged under A2, out = relu(h @ W3^T + b3)
    mlp_fused<<<(NDST + BM2 - 1) / BM2, 256, 0, stream>>>(
        h0, (const ushort*)fd_b, W1_b, W3_b, b1, b3, out);
}

// Round 20
// 145.056 us; speedup vs baseline: 1.0532x; 1.0532x over previous
//
#include <hip/hip_runtime.h>
#include <math.h>

#define NDST 50000
#define NSRC 50000
#define NEDGE 800000
#define DF 128

#define NBUK 1563          // ceil(NDST/32): dst bucket = dst >> 5
#define NCH 128            // edge chunks
#define EPC (NEDGE / NCH)  // 6250 edges per chunk
#define HN (NBUK * NCH)    // 200064 histogram cells
#define CAP 1536           // per-chunk LDS sort capacity

typedef __attribute__((ext_vector_type(4))) float f32x4;
typedef __attribute__((ext_vector_type(8))) short bf16x8;

__device__ __forceinline__ ushort f2bf(float f) {
    union { float f; unsigned int u; } c; c.f = f;
    unsigned int u = c.u;
    unsigned int r = (u + 0x7fffu + ((u >> 16) & 1u)) >> 16;   // RNE
    return (ushort)r;
}
__device__ __forceinline__ float bflo(unsigned int u) {
    union { unsigned int u; float f; } c; c.u = u << 16; return c.f;
}
__device__ __forceinline__ float bfhi(unsigned int u) {
    union { unsigned int u; float f; } c; c.u = u & 0xffff0000u; return c.f;
}

// ---------------- prep_all: GRID-STRIDE conv fs+fd + weights + coalesced hist zero ----
#define PB_FS 1500
#define PB_FD 1500
#define PB_W 320           // 81920 one-shot
#define PB_Z 196           // HN/4 uint4 one-shot
#define PB_TOT (PB_FS + PB_FD + PB_W + PB_Z)

__global__ void prep_all(const float* __restrict__ fs, unsigned int* __restrict__ fs_b,
                         const float* __restrict__ fd, unsigned int* __restrict__ fd_b,
                         uint4* __restrict__ hist4,
                         const float* __restrict__ W2, const float* __restrict__ W1,
                         const float* __restrict__ W3,
                         ushort* __restrict__ Wz_b, ushort* __restrict__ W1_b,
                         ushort* __restrict__ W3_b) {
    int b = blockIdx.x, tid = threadIdx.x;
    if (b < PB_FS + PB_FD) {
        const float* src = (b < PB_FS) ? fs : fd;
        unsigned int* dst = (b < PB_FS) ? fs_b : fd_b;
        int lb = (b < PB_FS) ? b : b - PB_FS;
        const int NU = NSRC * DF / 4;                 // 1.6M units of 4 floats
        for (int u = lb * 256 + tid; u < NU; u += PB_FS * 256) {
            float4 v = ((const float4*)src)[u];
            unsigned int lo = (unsigned int)f2bf(v.x) | ((unsigned int)f2bf(v.y) << 16);
            unsigned int hi = (unsigned int)f2bf(v.z) | ((unsigned int)f2bf(v.w) << 16);
            ((uint2*)dst)[u] = make_uint2(lo, hi);
        }
    } else if (b < PB_FS + PB_FD + PB_W) {
        int i = (b - PB_FS - PB_FD) * 256 + tid;      // one-shot, 81920 total
        if (i < 128 * 256) {
            int c = i >> 8, k = i & 255;
            float v = (k < 128) ? (W2[c * 384 + k] + W2[c * 384 + 128 + k])
                                : W2[c * 384 + 128 + k];
            Wz_b[i] = f2bf(v);
        } else if (i < 128 * 256 + 128 * 128) {
            int j = i - 128 * 256;
            W1_b[j] = f2bf(W1[j]);
        } else if (i < 128 * 256 + 128 * 128 + 128 * 256) {
            int j = i - 128 * 256 - 128 * 128;
            W3_b[j] = f2bf(W3[j]);
        }
    } else {
        int i = (b - PB_FS - PB_FD - PB_W) * 256 + tid;   // coalesced uint4 zero
        if (i < HN / 4) hist4[i] = make_uint4(0, 0, 0, 0);
    }
}

// ---------------- histogram (full-grid parallel, chunk from edge index) ----
__global__ void hist_k(const int* __restrict__ dst_idx, int* __restrict__ hist) {
    int e = blockIdx.x * 256 + threadIdx.x;
    if (e < NEDGE)
        atomicAdd(&hist[(dst_idx[e] >> 5) * NCH + (e / EPC)], 1);
}

// ---------------- generic 3-phase exclusive scan ----------------
__global__ void scan_bsums(const int* __restrict__ a, int* __restrict__ bsum, int n) {
    __shared__ int ws[4];
    int i = blockIdx.x * 256 + threadIdx.x;
    int v = (i < n) ? a[i] : 0;
    #pragma unroll
    for (int off = 32; off > 0; off >>= 1) v += __shfl_down(v, off, 64);
    if ((threadIdx.x & 63) == 0) ws[threadIdx.x >> 6] = v;
    __syncthreads();
    if (threadIdx.x == 0) bsum[blockIdx.x] = ws[0] + ws[1] + ws[2] + ws[3];
}

__global__ __launch_bounds__(256)
void scan_mid(const int* __restrict__ bsum, int* __restrict__ bpre, int nb) {
    __shared__ int part[256];
    int t = threadIdx.x;
    int ch = (nb + 255) / 256;
    int lo = t * ch, hi = min(nb, lo + ch);
    int s = 0;
    for (int i = lo; i < hi; ++i) s += bsum[i];
    part[t] = s;
    __syncthreads();
    for (int off = 1; off < 256; off <<= 1) {
        int v = (t >= off) ? part[t - off] : 0;
        __syncthreads();
        part[t] += v;
        __syncthreads();
    }
    int run = (t == 0) ? 0 : part[t - 1];
    for (int i = lo; i < hi; ++i) { bpre[i] = run; run += bsum[i]; }
}

__global__ __launch_bounds__(256)
void scan_final(const int* __restrict__ a, const int* __restrict__ bpre,
                int* __restrict__ out, int n) {
    __shared__ int s[256];
    int b = blockIdx.x, t = threadIdx.x;
    int i = b * 256 + t;
    int v = (i < n) ? a[i] : 0;
    s[t] = v;
    __syncthreads();
    for (int off = 1; off < 256; off <<= 1) {
        int u = (t >= off) ? s[t - off] : 0;
        __syncthreads();
        s[t] += u;
        __syncthreads();
    }
    if (i < n) out[i] = bpre[b] + s[t] - v;
}

// ---------------- partition: bucket-grouped (dlow<<16 | src) pairs ----------------
__global__ __launch_bounds__(256)
void partition_k(const int* __restrict__ src_idx, const int* __restrict__ dst_idx,
                 const int* __restrict__ scanned, unsigned int* __restrict__ pairs) {
    __shared__ int offs_l[NBUK];
    int c = blockIdx.x, tid = threadIdx.x;
    for (int i = tid; i < NBUK; i += 256) offs_l[i] = scanned[i * NCH + c];
    __syncthreads();
    int base = c * EPC;
    for (int e = base + tid; e < base + EPC; e += 256) {
        int d = dst_idx[e];
        int pos = atomicAdd(&offs_l[d >> 5], 1);
        pairs[pos] = (unsigned int)src_idx[e] | ((unsigned int)(d & 31) << 16);
    }
}

// ---------------- bucket aggregate: LDS counting-sort + REGISTER max/sum ----------------
__global__ __launch_bounds__(256)
void bucket_sort_agg(const unsigned int* __restrict__ fs_b,
                     const unsigned int* __restrict__ pairs,
                     const int* __restrict__ scanned,
                     unsigned int* __restrict__ mx_b, unsigned int* __restrict__ sm_b) {
    __shared__ int s_src[CAP];
    __shared__ int s_cnt[32], s_off[32], s_cur[32];
    int B = blockIdx.x, tid = threadIdx.x;
    int w = tid >> 6, lane = tid & 63;
    int s0 = scanned[B * NCH];
    int s1 = (B + 1 < NBUK) ? scanned[(B + 1) * NCH] : NEDGE;

    float mx0[8], mx1[8], sm0[8], sm1[8];
    #pragma unroll
    for (int j = 0; j < 8; ++j) {
        mx0[j] = -INFINITY; mx1[j] = -INFINITY; sm0[j] = 0.f; sm1[j] = 0.f;
    }

    for (int cs = s0; cs < s1; cs += CAP) {
        int n = min(CAP, s1 - cs);
        if (tid < 32) s_cnt[tid] = 0;
        __syncthreads();
        for (int i = tid; i < n; i += 256)
            atomicAdd(&s_cnt[(pairs[cs + i] >> 16) & 31u], 1);
        __syncthreads();
        if (tid < 32) {                      // wave 0: 32-wide shfl scan
            int v = s_cnt[tid];
            int incl = v;
            #pragma unroll
            for (int d = 1; d < 32; d <<= 1) {
                int o = __shfl_up(incl, d, 64);
                if (tid >= d) incl += o;
            }
            s_off[tid] = incl - v;
            s_cur[tid] = incl - v;
        }
        __syncthreads();
        for (int i = tid; i < n; i += 256) {
            unsigned int p = pairs[cs + i];
            int pos = atomicAdd(&s_cur[(p >> 16) & 31u], 1);
            s_src[pos] = (int)(p & 0xFFFFu);
        }
        __syncthreads();
        #pragma unroll
        for (int j = 0; j < 8; ++j) {
            int dl = w * 8 + j;
            int e = s_off[dl], eend = e + s_cnt[dl];
            for (; e + 7 < eend; e += 8) {          // 8 outstanding row loads
                unsigned int u0 = fs_b[(size_t)s_src[e] * 64 + lane];
                unsigned int u1 = fs_b[(size_t)s_src[e + 1] * 64 + lane];
                unsigned int u2 = fs_b[(size_t)s_src[e + 2] * 64 + lane];
                unsigned int u3 = fs_b[(size_t)s_src[e + 3] * 64 + lane];
                unsigned int u4 = fs_b[(size_t)s_src[e + 4] * 64 + lane];
                unsigned int u5 = fs_b[(size_t)s_src[e + 5] * 64 + lane];
                unsigned int u6 = fs_b[(size_t)s_src[e + 6] * 64 + lane];
                unsigned int u7 = fs_b[(size_t)s_src[e + 7] * 64 + lane];
                float a0 = bflo(u0), c0 = bfhi(u0);
                float a1 = bflo(u1), c1 = bfhi(u1);
                float a2 = bflo(u2), c2 = bfhi(u2);
                float a3 = bflo(u3), c3 = bfhi(u3);
                float a4 = bflo(u4), c4 = bfhi(u4);
                float a5 = bflo(u5), c5 = bfhi(u5);
                float a6 = bflo(u6), c6 = bfhi(u6);
                float a7 = bflo(u7), c7 = bfhi(u7);
                mx0[j] = fmaxf(mx0[j], fmaxf(fmaxf(fmaxf(a0, a1), fmaxf(a2, a3)),
                                             fmaxf(fmaxf(a4, a5), fmaxf(a6, a7))));
                mx1[j] = fmaxf(mx1[j], fmaxf(fmaxf(fmaxf(c0, c1), fmaxf(c2, c3)),
                                             fmaxf(fmaxf(c4, c5), fmaxf(c6, c7))));
                sm0[j] += ((a0 + a1) + (a2 + a3)) + ((a4 + a5) + (a6 + a7));
                sm1[j] += ((c0 + c1) + (c2 + c3)) + ((c4 + c5) + (c6 + c7));
            }
            for (; e + 3 < eend; e += 4) {
                unsigned int u0 = fs_b[(size_t)s_src[e] * 64 + lane];
                unsigned int u1 = fs_b[(size_t)s_src[e + 1] * 64 + lane];
                unsigned int u2 = fs_b[(size_t)s_src[e + 2] * 64 + lane];
                unsigned int u3 = fs_b[(size_t)s_src[e + 3] * 64 + lane];
                float a0 = bflo(u0), c0 = bfhi(u0);
                float a1 = bflo(u1), c1 = bfhi(u1);
                float a2 = bflo(u2), c2 = bfhi(u2);
                float a3 = bflo(u3), c3 = bfhi(u3);
                mx0[j] = fmaxf(fmaxf(fmaxf(mx0[j], a0), a1), fmaxf(a2, a3));
                mx1[j] = fmaxf(fmaxf(fmaxf(mx1[j], c0), c1), fmaxf(c2, c3));
                sm0[j] += (a0 + a1) + (a2 + a3);
                sm1[j] += (c0 + c1) + (c2 + c3);
            }
            for (; e < eend; ++e) {
                unsigned int u = fs_b[(size_t)s_src[e] * 64 + lane];
                float a = bflo(u), c = bfhi(u);
                mx0[j] = fmaxf(mx0[j], a);
                mx1[j] = fmaxf(mx1[j], c);
                sm0[j] += a;
                sm1[j] += c;
            }
        }
        __syncthreads();                     // LDS reused next chunk
    }

    int base_d = B * 32;
    #pragma unroll
    for (int j = 0; j < 8; ++j) {
        int d = base_d + w * 8 + j;
        if (d >= NDST) continue;
        float m0 = mx0[j], m1 = mx1[j];
        if (m0 == -INFINITY) m0 = 0.f;       // zero-degree dst
        if (m1 == -INFINITY) m1 = 0.f;
        union { float f; unsigned int u; } c0, c1;
        c0.f = m0; c1.f = m1;                // maxima of bf16 values: exact truncation
        size_t o = (size_t)d * 64 + lane;
        mx_b[o] = (c0.u >> 16) | (c1.u & 0xFFFF0000u);
        sm_b[o] = (unsigned int)f2bf(sm0[j]) | ((unsigned int)f2bf(sm1[j]) << 16);
    }
}

// ---------------- fused MLP: R10 schedule, HALF-SIZE blocks (BM2=32) ----------------
// Same pipeline (W one step ahead regs->LDS; phase-wide A preload), but each
// wave owns ONE 16-row m-tile: Hs halves -> LDS 26.9KB -> 5 blocks/CU.
#define BM2 32
#define LDH 260    // Hs row stride: 4 rbase-groups -> banks {0,8,16,24}, 2-way only
#define LDWS 40    // Ws row stride (80B, 16B-aligned)

__global__ __launch_bounds__(256)
void mlp_fused(const ushort* __restrict__ mxa, const ushort* __restrict__ sma,
               const ushort* __restrict__ fdb,
               const ushort* __restrict__ Wz_b, const ushort* __restrict__ W1_b,
               const ushort* __restrict__ W3_b,
               const float* __restrict__ b1, const float* __restrict__ b2,
               const float* __restrict__ b3,
               float* __restrict__ out) {
    __shared__ ushort Hs[BM2 * LDH];     // 16.6 KB
    __shared__ ushort Ws[128 * LDWS];    // 10.2 KB  -> total 26.9 KB, 5 blocks/CU
    int tid = threadIdx.x;
    int bm = blockIdx.x * BM2;
    int wid = tid >> 6, lane = tid & 63;
    int wm = (wid & 1) * 16, wn = (wid >> 1) * 64;
    int lrow = lane & 15, lk8 = (lane >> 4) * 8;
    int rbase = (lane >> 4) * 4;

    int am0 = min(bm + wm + lrow, NDST - 1);          // clamped; OOB never stored
    int bn[4];
    #pragma unroll
    for (int ni = 0; ni < 4; ++ni) bn[ni] = wn + ni * 16 + lrow;

    int srw = tid >> 1, skw = (tid & 1) * 16;         // W staging coords
    uint4 wr0, wr1;                                    // W regs (one step ahead)
    f32x4 acc[4];

#define STAGE_LOAD(Wb, K, k0) { const ushort* wp = (Wb) + (size_t)srw * (K) + (k0) + skw; \
                                wr0 = *(const uint4*)wp; wr1 = *(const uint4*)(wp + 8); }
#define STAGE_WRITE() { *(uint4*)&Ws[srw * LDWS + skw] = wr0; \
                        *(uint4*)&Ws[srw * LDWS + skw + 8] = wr1; }

    // prologue: W step0 + ALL A1 fragments in flight (8 independent loads)
    STAGE_LOAD(Wz_b, 256, 0);
    bf16x8 pA[8];                         // A1 frags: row am0, 8 K-steps
    #pragma unroll
    for (int k = 0; k < 8; ++k) {
        const ushort* ap = (k < 4) ? mxa : sma;
        int kl = ((k * 32) & 127) + lk8;
        pA[k] = *(const bf16x8*)(ap + (size_t)am0 * 128 + kl);
    }

    // ---------- phase A1: h[:,0:128] = relu([mx|sm] @ Wz^T + b2), K=256 ----------
    #pragma unroll
    for (int j = 0; j < 4; ++j) acc[j] = (f32x4){0.f, 0.f, 0.f, 0.f};
    #pragma unroll
    for (int k = 0; k < 8; ++k) {
        if (k) __syncthreads();            // prev step's Ws readers done
        STAGE_WRITE();
        __syncthreads();                   // Ws ready
        if (k < 7) { STAGE_LOAD(Wz_b, 256, (k + 1) * 32); }
        else       { STAGE_LOAD(W1_b, 128, 0); }            // next phase's W
        #pragma unroll
        for (int ni = 0; ni < 4; ++ni) {
            bf16x8 bf = *(const bf16x8*)&Ws[bn[ni] * LDWS + lk8];
            acc[ni] = __builtin_amdgcn_mfma_f32_16x16x32_bf16(pA[k], bf, acc[ni], 0, 0, 0);
        }
    }
    // issue ALL A2 fragments now -- they ride under the Hs epilogue writes
    bf16x8 qA[4];
    #pragma unroll
    for (int k = 0; k < 4; ++k)
        qA[k] = *(const bf16x8*)(fdb + (size_t)am0 * 128 + k * 32 + lk8);
    #pragma unroll
    for (int ni = 0; ni < 4; ++ni) {
        float bv = b2[bn[ni]];
        #pragma unroll
        for (int r = 0; r < 4; ++r)
            Hs[(wm + rbase + r) * LDH + bn[ni]] = f2bf(fmaxf(acc[ni][r] + bv, 0.f));
    }

    // ---------- phase A2: h[:,128:256] = relu(fd @ W1^T + b1), K=128 ----------
    #pragma unroll
    for (int j = 0; j < 4; ++j) acc[j] = (f32x4){0.f, 0.f, 0.f, 0.f};
    #pragma unroll
    for (int k = 0; k < 4; ++k) {
        __syncthreads();                   // prev Ws readers done
        STAGE_WRITE();
        __syncthreads();
        if (k < 3) { STAGE_LOAD(W1_b, 128, (k + 1) * 32); }
        else       { STAGE_LOAD(W3_b, 256, 0); }             // phase B's W
        #pragma unroll
        for (int ni = 0; ni < 4; ++ni) {
            bf16x8 bf = *(const bf16x8*)&Ws[bn[ni] * LDWS + lk8];
            acc[ni] = __builtin_amdgcn_mfma_f32_16x16x32_bf16(qA[k], bf, acc[ni], 0, 0, 0);
        }
    }
    #pragma unroll
    for (int ni = 0; ni < 4; ++ni) {
        float bv = b1[bn[ni]];
        #pragma unroll
        for (int r = 0; r < 4; ++r)
            Hs[(wm + rbase + r) * LDH + 128 + bn[ni]] = f2bf(fmaxf(acc[ni][r] + bv, 0.f));
    }

    // ---------- phase B: out = relu(h @ W3^T + b3), K=256, A from LDS ----------
    #pragma unroll
    for (int j = 0; j < 4; ++j) acc[j] = (f32x4){0.f, 0.f, 0.f, 0.f};
    #pragma unroll
    for (int k = 0; k < 8; ++k) {
        __syncthreads();                   // k=0: all Hs writes visible; else Ws readers done
        STAGE_WRITE();
        __syncthreads();
        if (k < 7) { STAGE_LOAD(W3_b, 256, (k + 1) * 32); }
        bf16x8 af0 = *(const bf16x8*)&Hs[(wm + lrow) * LDH + k * 32 + lk8];
        #pragma unroll
        for (int ni = 0; ni < 4; ++ni) {
            bf16x8 bf = *(const bf16x8*)&Ws[bn[ni] * LDWS + lk8];
            acc[ni] = __builtin_amdgcn_mfma_f32_16x16x32_bf16(af0, bf, acc[ni], 0, 0, 0);
        }
    }
    #pragma unroll
    for (int ni = 0; ni < 4; ++ni) {
        float bv = b3[bn[ni]];
        #pragma unroll
        for (int r = 0; r < 4; ++r) {
            int m = bm + wm + rbase + r;
            if (m < NDST)
                out[(size_t)m * 128 + bn[ni]] = fmaxf(acc[ni][r] + bv, 0.f);
        }
    }
#undef STAGE_LOAD
#undef STAGE_WRITE
}

extern "C" void kernel_launch(void* const* d_in, const int* in_sizes, int n_in,
                              void* d_out, int out_size, void* d_ws, size_t ws_size,
                              hipStream_t stream) {
    const float* feat_src = (const float*)d_in[0];
    const float* feat_dst = (const float*)d_in[1];
    const float* W1 = (const float*)d_in[2];
    const float* b1 = (const float*)d_in[3];
    const float* W2 = (const float*)d_in[4];
    const float* b2 = (const float*)d_in[5];
    const float* W3 = (const float*)d_in[6];
    const float* b3 = (const float*)d_in[7];
    const int* src_idx = (const int*)d_in[8];
    const int* dst_idx = (const int*)d_in[9];

    float* out = (float*)d_out;

    unsigned int* fs_b = (unsigned int*)d_ws;                 // NSRC*64 u32
    unsigned int* mx_b = fs_b + (size_t)NSRC * 64;            // NDST*64 u32
    unsigned int* sm_b = mx_b + (size_t)NDST * 64;            // NDST*64 u32
    unsigned int* fd_b = sm_b + (size_t)NDST * 64;            // NDST*64 u32
    ushort* Wz_b = (ushort*)(fd_b + (size_t)NDST * 64);       // 128*256
    ushort* W1_b = Wz_b + 128 * 256;                          // 128*128
    ushort* W3_b = W1_b + 128 * 128;                          // 128*256
    int* hist    = (int*)(W3_b + 128 * 256);                  // HN (16B aligned)
    int* scanned = hist + HN;                                 // HN
    int* bsum    = scanned + HN;                              // 1024
    int* bpre    = bsum + 1024;                               // 1024
    unsigned int* pairs = (unsigned int*)(bpre + 1024);       // NEDGE

    const int NBH = (HN + 255) / 256;   // 782 scan blocks

    // prep: grid-stride feat conversions + weights + coalesced hist zero
    prep_all<<<PB_TOT, 256, 0, stream>>>(
        feat_src, fs_b, feat_dst, fd_b, (uint4*)hist, W2, W1, W3, Wz_b, W1_b, W3_b);

    // histogram (full-grid) + scan + partition
    hist_k<<<(NEDGE + 255) / 256, 256, 0, stream>>>(dst_idx, hist);
    scan_bsums<<<NBH, 256, 0, stream>>>(hist, bsum, HN);
    scan_mid<<<1, 256, 0, stream>>>(bsum, bpre, NBH);
    scan_final<<<NBH, 256, 0, stream>>>(hist, bpre, scanned, HN);
    partition_k<<<NCH, 256, 0, stream>>>(src_idx, dst_idx, scanned, pairs);

    // aggregation: LDS-sorted bucket, register accumulation, 8-deep gather
    bucket_sort_agg<<<NBUK, 256, 0, stream>>>(fs_b, pairs, scanned, mx_b, sm_b);

    // fused MLP (BM2=32, 5 blocks/CU): z2|z1 -> Hs -> out
    mlp_fused<<<(NDST + BM2 - 1) / BM2, 256, 0, stream>>>(
        (const ushort*)mx_b, (const ushort*)sm_b, (const ushort*)fd_b,
        Wz_b, W1_b, W3_b, b1, b2, b3, out);
}